// Round 7
// baseline (229.982 us; speedup 1.0000x reference)
//
#include <hip/hip_runtime.h>

// Problem constants: h[B,G,D], W[G,D,K], out[B,G,K]
#define Gn   100
#define Bn   256
#define Dn   768
#define Kn   128
#define LDP  40   // LDS leading dim in shorts (32+8)
#define KT   4    // split-K factor: 4 d-ranges of 192

typedef __attribute__((ext_vector_type(8))) short short8;
typedef __attribute__((ext_vector_type(4))) float f32x4;

// pack two fp32 -> two bf16 (round-to-nearest, ties away) in 3 VALU
__device__ inline unsigned pack2(float lo, float hi) {
  union { float f; unsigned u; } a, b; a.f = lo; b.f = hi;
  return __builtin_amdgcn_perm(b.u + 0x8000u, a.u + 0x8000u, 0x07060302u);
}

// Non-draining block barrier: execution sync + LDS-write visibility ONLY.
__device__ inline void barrier_nodrain() {
  asm volatile("s_waitcnt lgkmcnt(0)\n\ts_barrier" ::: "memory");
}

// ============================ R7 split-K path ============================
// Rationale: R0/R3/R4/R5/R6 (reg-staged depth 1/2/3, DMA+counted-vmcnt) all
// converge at ~6-8 B/cyc/CU of vector-load fill with every pipe <17% busy:
// per-CU outstanding-request limit x L3-ish latency sets the rate; only more
// independent blocks/CUs raise throughput (R0: 3.25 blk/CU => 8 B/cyc/CU).
// 128x128 tiles gave minimal traffic (157 MB) but only 200 blocks (56 CUs
// idle, no overlap). Split-K=4 keeps the tile + traffic and yields 800
// blocks at 3 resident/CU. Partial dots atomicAdd into pre-zeroed out;
// per-kt ssq partials -> ws (written, not atomic: single writer per slot);
// second kernel folds norms and rescales.
// ws layout (floats): AW[kt][g][256] @ 0 (102400), BW[kt][g][128] @ 102400
// (51200). Total 153600 floats = 614400 B.
struct SAS { float4 a0, a1, a2, a3; };       // rows ar, ar+64: 8 k each
struct SBS { float2 b0, b1, b2, b3, b4, b5, b6, b7; };

__global__ __launch_bounds__(256, 3) void groupfc_splitk(
    const float* __restrict__ h, const float* __restrict__ W,
    float* __restrict__ out, float* __restrict__ ws) {
  // grid 832 = 13*64; xcd=id&7; q=id>>3: tk=q&7 (mt*4+kt), gh=q>>3 (0..12);
  // g=gh*8+xcd. All 8 blocks of a group land on one XCD (B re-read L2-hits).
  const int id  = blockIdx.x;
  const int xcd = id & 7;
  const int q   = id >> 3;
  const int tk  = q & 7;
  const int gh  = q >> 3;
  const int g   = gh * 8 + xcd;
  if (g >= Gn) return;                       // pad blocks exit pre-barrier
  const int mt  = tk >> 2;                   // 0..1 (rows of 128)
  const int kt  = tk & 3;                    // 0..3 (d-range of 192)

  const int t    = threadIdx.x;
  const int lane = t & 63;
  const int wave = t >> 6;                   // 0..3
  const int wm   = wave >> 1, wn = wave & 1; // 2x2 wave grid, 64x64 each
  const int l15  = lane & 15, quad = lane >> 4;

  __shared__ __align__(16) short Af[2][128 * LDP];  // [m][k] bf16
  __shared__ __align__(16) short Bf[2][128 * LDP];  // [n][k] bf16
  __shared__ float BssqL[4][128];

  f32x4 acc[4][4];
#pragma unroll
  for (int mi = 0; mi < 4; ++mi)
#pragma unroll
    for (int ni = 0; ni < 4; ++ni) acc[mi][ni] = (f32x4){0.f, 0.f, 0.f, 0.f};

  // A staging: thread -> rows ar & ar+64, 8 contiguous k at ac (2x dwordx4 ea)
  const int ar = t >> 2;                     // 0..63
  const int ac = (t & 3) * 8;
  const float* aptr  = h + ((size_t)(mt * 128 + ar) * Gn + g) * Dn + kt * 192 + ac;
  const float* aptr2 = aptr + (size_t)64 * Gn * Dn;

  // B staging: thread -> col pair c2..c2+1, 8 d-rows at bq*8 (8x dwordx2)
  const int c2 = lane * 2;                   // 0..126
  const int bq = wave;                       // 0..3
  const float* bptr = W + (size_t)g * (Dn * Kn)
                        + (size_t)(kt * 192 + bq * 8) * Kn + c2;

  const int koff = quad * 8;
  const int m0   = wm * 64 + l15;
  const int n0   = wn * 64 + l15;

  float asq0 = 0.f, asq1 = 0.f, bs0 = 0.f, bs1 = 0.f;
  SAS A;                                     // single set (depth-1; R3 proved
  SBS Bs;                                    // depth doesn't matter) -> low VGPR

  auto load_set = [&](int c) {
    const int d0 = c * 32;
    A.a0 = *(const float4*)(aptr + d0);
    A.a1 = *(const float4*)(aptr + d0 + 4);
    A.a2 = *(const float4*)(aptr2 + d0);
    A.a3 = *(const float4*)(aptr2 + d0 + 4);
    const float* bp = bptr + (size_t)d0 * Kn;
    Bs.b0 = *(const float2*)(bp);
    Bs.b1 = *(const float2*)(bp + Kn);
    Bs.b2 = *(const float2*)(bp + 2 * Kn);
    Bs.b3 = *(const float2*)(bp + 3 * Kn);
    Bs.b4 = *(const float2*)(bp + 4 * Kn);
    Bs.b5 = *(const float2*)(bp + 5 * Kn);
    Bs.b6 = *(const float2*)(bp + 6 * Kn);
    Bs.b7 = *(const float2*)(bp + 7 * Kn);
  };

  auto pack_set = [&](int buf) {
    const float4 a0 = A.a0, a1 = A.a1, a2 = A.a2, a3 = A.a3;
    asq0 += a0.x*a0.x + a0.y*a0.y + a0.z*a0.z + a0.w*a0.w
          + a1.x*a1.x + a1.y*a1.y + a1.z*a1.z + a1.w*a1.w;
    asq1 += a2.x*a2.x + a2.y*a2.y + a2.z*a2.z + a2.w*a2.w
          + a3.x*a3.x + a3.y*a3.y + a3.z*a3.z + a3.w*a3.w;
    uint4 ap;
    ap.x = pack2(a0.x, a0.y); ap.y = pack2(a0.z, a0.w);
    ap.z = pack2(a1.x, a1.y); ap.w = pack2(a1.z, a1.w);
    *(uint4*)&Af[buf][ar * LDP + ac] = ap;
    ap.x = pack2(a2.x, a2.y); ap.y = pack2(a2.z, a2.w);
    ap.z = pack2(a3.x, a3.y); ap.w = pack2(a3.z, a3.w);
    *(uint4*)&Af[buf][(ar + 64) * LDP + ac] = ap;

    const float2 b0 = Bs.b0, b1 = Bs.b1, b2 = Bs.b2, b3 = Bs.b3,
                 b4 = Bs.b4, b5 = Bs.b5, b6 = Bs.b6, b7 = Bs.b7;
    bs0 += b0.x*b0.x + b1.x*b1.x + b2.x*b2.x + b3.x*b3.x
         + b4.x*b4.x + b5.x*b5.x + b6.x*b6.x + b7.x*b7.x;
    bs1 += b0.y*b0.y + b1.y*b1.y + b2.y*b2.y + b3.y*b3.y
         + b4.y*b4.y + b5.y*b5.y + b6.y*b6.y + b7.y*b7.y;
    uint4 w0, w1;
    w0.x = pack2(b0.x, b1.x); w0.y = pack2(b2.x, b3.x);
    w0.z = pack2(b4.x, b5.x); w0.w = pack2(b6.x, b7.x);
    w1.x = pack2(b0.y, b1.y); w1.y = pack2(b2.y, b3.y);
    w1.z = pack2(b4.y, b5.y); w1.w = pack2(b6.y, b7.y);
    *(uint4*)&Bf[buf][c2 * LDP + bq * 8]       = w0;
    *(uint4*)&Bf[buf][(c2 + 1) * LDP + bq * 8] = w1;
  };

  auto mfma_step = [&](int buf) {
    short8 af[4], bf[4];
#pragma unroll
    for (int mi = 0; mi < 4; ++mi)
      af[mi] = *(const short8*)&Af[buf][(m0 + mi * 16) * LDP + koff];
#pragma unroll
    for (int ni = 0; ni < 4; ++ni)
      bf[ni] = *(const short8*)&Bf[buf][(n0 + ni * 16) * LDP + koff];
#pragma unroll
    for (int mi = 0; mi < 4; ++mi)
#pragma unroll
      for (int ni = 0; ni < 4; ++ni)
        acc[mi][ni] = __builtin_amdgcn_mfma_f32_16x16x32_bf16(
            af[mi], bf[ni], acc[mi][ni], 0, 0, 0);
  };

  // ---- 6 chunks of 32; 2 LDS buffers; pack chunk s+1 in phase s ----
  load_set(0);
  pack_set(0);
  // phase s: [S holds chunk s+1 after load below] ... order per phase:
  //   load(s+1); BAR; mfma(buf s%2); pack(S -> buf (s+1)%2)
  // Races: pack(buf X) at phase s happens after BAR(s); buf X's readers ran
  // at phase s-1 before BAR(s). Visibility via BAR(s+1)+lgkmcnt(0).
  load_set(1); barrier_nodrain(); mfma_step(0); pack_set(1);
  load_set(2); barrier_nodrain(); mfma_step(1); pack_set(0);
  load_set(3); barrier_nodrain(); mfma_step(0); pack_set(1);
  load_set(4); barrier_nodrain(); mfma_step(1); pack_set(0);
  load_set(5); barrier_nodrain(); mfma_step(0); pack_set(1);
               barrier_nodrain(); mfma_step(1);

  // ---- ssq partials -> ws (single writer per slot; no zeroing needed) ----
  asq0 += __shfl_xor(asq0, 1); asq0 += __shfl_xor(asq0, 2);
  asq1 += __shfl_xor(asq1, 1); asq1 += __shfl_xor(asq1, 2);
  if ((t & 3) == 0) {                        // A[row,d] touched by ONE block
    ws[kt * 25600 + g * 256 + mt * 128 + ar]      = asq0;
    ws[kt * 25600 + g * 256 + mt * 128 + ar + 64] = asq1;
  }
  BssqL[bq][c2]     = bs0;                   // B read by both mt blocks:
  BssqL[bq][c2 + 1] = bs1;                   // only mt==0 contributes
  __syncthreads();
  if (mt == 0 && t < 128) {
    const float bsum = BssqL[0][t] + BssqL[1][t] + BssqL[2][t] + BssqL[3][t];
    ws[102400 + kt * 12800 + g * 128 + t] = bsum;
  }

  // ---- partial dots: atomicAdd into pre-zeroed out ----
  // C/D layout: col = lane&15, row = quad*4 + reg
#pragma unroll
  for (int mi = 0; mi < 4; ++mi) {
#pragma unroll
    for (int r = 0; r < 4; ++r) {
      const int grow = mt * 128 + wm * 64 + mi * 16 + quad * 4 + r;
      float* op = out + ((size_t)grow * Gn + g) * Kn;
#pragma unroll
      for (int ni = 0; ni < 4; ++ni)
        atomicAdd(&op[wn * 64 + ni * 16 + l15], acc[mi][ni][r]);
    }
  }
}

// normalize: out[row,g,col] *= 1/max(||h_row||,eps) * 1/max(||w_col||,eps)
__global__ __launch_bounds__(128) void groupfc_norm(
    const float* __restrict__ ws, float* __restrict__ out) {
  const int bid = blockIdx.x;                // 0..25599
  const int g   = bid % Gn;
  const int row = bid / Gn;                  // 0..255
  const float as = ws[g * 256 + row]         + ws[25600 + g * 256 + row]
                 + ws[51200 + g * 256 + row] + ws[76800 + g * 256 + row];
  const float hs = 1.0f / fmaxf(sqrtf(as), 1e-12f);
  const int col = threadIdx.x;
  const float* BW = ws + 102400;
  const float bs = BW[g * 128 + col]         + BW[12800 + g * 128 + col]
                 + BW[25600 + g * 128 + col] + BW[38400 + g * 128 + col];
  const float wc = 1.0f / fmaxf(sqrtf(bs), 1e-12f);
  const size_t i = ((size_t)row * Gn + g) * Kn + col;
  out[i] *= hs * wc;
}

// ===================== R6 fallback (ws too small) =======================
typedef __attribute__((ext_vector_type(8))) short short8_fb;

__device__ inline void gload16(const float* g, float* l) {
  __builtin_amdgcn_global_load_lds(
      (const __attribute__((address_space(1))) void*)g,
      (__attribute__((address_space(3))) void*)l, 16, 0, 0);
}

__global__ __launch_bounds__(512, 2) void groupfc_kernel(
    const float* __restrict__ h, const float* __restrict__ W,
    float* __restrict__ out) {
  const int id  = blockIdx.x;
  const int xcd = id & 7;
  const int j   = id >> 3;
  const int mt  = j & 1;
  const int g   = xcd + (j >> 1) * 8;
  if (g >= Gn) return;

  const int t    = threadIdx.x;
  const int lane = t & 63;
  const int w    = t >> 6;
  const int wm   = w >> 2;
  const int wn   = w & 3;
  const int l15  = lane & 15, quad = lane >> 4;

  __shared__ __align__(16) float Af[4][128 * 32];
  __shared__ __align__(16) float Bf[4][32 * 128];
  __shared__ float AssqL[128];
  __shared__ float BssqL[128];

  f32x4 acc[4][2];
#pragma unroll
  for (int mi = 0; mi < 4; ++mi)
#pragma unroll
    for (int ni = 0; ni < 2; ++ni) acc[mi][ni] = (f32x4){0.f, 0.f, 0.f, 0.f};

  const int arow0 = w * 16 + (lane >> 3);
  const int axor  = (lane & 7) ^ ((lane >> 3) & 7);
  const float* asrc0 = h + ((size_t)(mt * 128 + arow0) * Gn + g) * Dn + 4 * axor;
  const float* asrc1 = h + ((size_t)(mt * 128 + arow0 + 8) * Gn + g) * Dn + 4 * axor;
  const float* Wg = W + (size_t)g * (Dn * Kn);
  const int dd0 = w * 4 + (lane >> 5);
  const int dd1 = dd0 + 2;
  const float* bsrc0 = Wg + (size_t)dd0 * Kn + 4 * ((lane & 31) ^ ((dd0 >> 3) << 2));
  const float* bsrc1 = Wg + (size_t)dd1 * Kn + 4 * ((lane & 31) ^ ((dd1 >> 3) << 2));
  const int ldsq = w * 512;

  auto issue = [&](int tile, float* AbW, float* BbW) {
    const size_t ad = (size_t)tile * 32;
    const size_t bd = (size_t)tile * 32 * Kn;
    gload16(asrc0 + ad, AbW + ldsq);
    gload16(asrc1 + ad, AbW + ldsq + 256);
    gload16(bsrc0 + bd, BbW + ldsq);
    gload16(bsrc1 + bd, BbW + ldsq + 256);
  };

  const int aBase = (wm * 64 + l15) * 32;
  const int ac0   = ((quad * 2) ^ (l15 & 7)) * 4;
  const int ac1   = ((quad * 2 + 1) ^ (l15 & 7)) * 4;
  const int col0 = wn * 32 + l15;
  const int col1 = col0 + 16;
  const int b0   = quad * 1024 + (((col0 >> 2) ^ (quad << 2)) << 2) + (l15 & 3);
  const int b1   = quad * 1024 + (((col1 >> 2) ^ (quad << 2)) << 2) + (l15 & 3);

  float asq[4] = {0.f, 0.f, 0.f, 0.f};
  float bsq[2] = {0.f, 0.f};

  auto compute = [&](const float* Ab, const float* Bb) {
    short8 af[4], bf[2];
#pragma unroll
    for (int mi = 0; mi < 4; ++mi) {
      const f32x4 x0 = *(const f32x4*)&Ab[aBase + mi * 512 + ac0];
      const f32x4 x1 = *(const f32x4*)&Ab[aBase + mi * 512 + ac1];
      union { uint4 u; short8 s; } r;
      r.u.x = pack2(x0.x, x0.y); r.u.y = pack2(x0.z, x0.w);
      r.u.z = pack2(x1.x, x1.y); r.u.w = pack2(x1.z, x1.w);
      af[mi] = r.s;
      if (wn == 0)
        asq[mi] += x0.x*x0.x + x0.y*x0.y + x0.z*x0.z + x0.w*x0.w
                 + x1.x*x1.x + x1.y*x1.y + x1.z*x1.z + x1.w*x1.w;
    }
#pragma unroll
    for (int ni = 0; ni < 2; ++ni) {
      const int bb = ni ? b1 : b0;
      float z0 = Bb[bb],           z1 = Bb[bb + 128],
            z2 = Bb[bb + 2 * 128], z3 = Bb[bb + 3 * 128],
            z4 = Bb[bb + 4 * 128], z5 = Bb[bb + 5 * 128],
            z6 = Bb[bb + 6 * 128], z7 = Bb[bb + 7 * 128];
      union { uint4 u; short8 s; } r;
      r.u.x = pack2(z0, z1); r.u.y = pack2(z2, z3);
      r.u.z = pack2(z4, z5); r.u.w = pack2(z6, z7);
      bf[ni] = r.s;
      if (wm == 0)
        bsq[ni] += z0*z0 + z1*z1 + z2*z2 + z3*z3 + z4*z4 + z5*z5 + z6*z6 + z7*z7;
    }
#pragma unroll
    for (int mi = 0; mi < 4; ++mi)
#pragma unroll
      for (int ni = 0; ni < 2; ++ni)
        acc[mi][ni] = __builtin_amdgcn_mfma_f32_16x16x32_bf16(
            af[mi], bf[ni], acc[mi][ni], 0, 0, 0);
  };

#define VMW(N) asm volatile("s_waitcnt vmcnt(" #N ")" ::: "memory")
#define BAR()  asm volatile("s_barrier" ::: "memory")

  issue(0, Af[0], Bf[0]);
  issue(1, Af[1], Bf[1]);

  for (int tt = 0; tt < 20; tt += 4) {
    issue(tt + 2, Af[2], Bf[2]); VMW(8); BAR(); compute(Af[0], Bf[0]);
    issue(tt + 3, Af[3], Bf[3]); VMW(8); BAR(); compute(Af[1], Bf[1]);
    issue(tt + 4, Af[0], Bf[0]); VMW(8); BAR(); compute(Af[2], Bf[2]);
    issue(tt + 5, Af[1], Bf[1]); VMW(8); BAR(); compute(Af[3], Bf[3]);
  }
  issue(22, Af[2], Bf[2]); VMW(8); BAR(); compute(Af[0], Bf[0]);
  issue(23, Af[3], Bf[3]); VMW(8); BAR(); compute(Af[1], Bf[1]);
  VMW(4); BAR(); compute(Af[2], Bf[2]);
  VMW(0); BAR(); compute(Af[3], Bf[3]);

#undef VMW
#undef BAR

  if (wn == 0) {
#pragma unroll
    for (int mi = 0; mi < 4; ++mi) {
      asq[mi] += __shfl_xor(asq[mi], 16);
      asq[mi] += __shfl_xor(asq[mi], 32);
      if (quad == 0) AssqL[wm * 64 + mi * 16 + l15] = asq[mi];
    }
  }
  if (wm == 0) {
#pragma unroll
    for (int ni = 0; ni < 2; ++ni) {
      bsq[ni] += __shfl_xor(bsq[ni], 16);
      bsq[ni] += __shfl_xor(bsq[ni], 32);
      if (quad == 0) BssqL[wn * 32 + ni * 16 + l15] = bsq[ni];
    }
  }
  __syncthreads();

  const float wi0 = 1.0f / fmaxf(sqrtf(BssqL[col0]), 1e-12f);
  const float wi1 = 1.0f / fmaxf(sqrtf(BssqL[col1]), 1e-12f);

#pragma unroll
  for (int mi = 0; mi < 4; ++mi) {
#pragma unroll
    for (int r = 0; r < 4; ++r) {
      const int lr = wm * 64 + mi * 16 + quad * 4 + r;
      const float hs = 1.0f / fmaxf(sqrtf(AssqL[lr]), 1e-12f);
      const int row = mt * 128 + lr;
      const size_t ob = ((size_t)row * Gn + g) * Kn;
      out[ob + col0] = acc[mi][0][r] * hs * wi0;
      out[ob + col1] = acc[mi][1][r] * hs * wi1;
    }
  }
}

extern "C" void kernel_launch(void* const* d_in, const int* in_sizes, int n_in,
                              void* d_out, int out_size, void* d_ws, size_t ws_size,
                              hipStream_t stream) {
  const float* h = (const float*)d_in[0];          // [B,G,D]
  const float* W = (const float*)d_in[1];          // [G,D,K]
  float* out = (float*)d_out;                      // [B,G,K]
  if (d_ws && ws_size >= 614400) {
    // split-K: partial dots atomicAdd into pre-zeroed out; ssq partials in ws
    hipLaunchKernelGGL(groupfc_splitk, dim3(832), dim3(256), 0, stream,
                       h, W, out, (float*)d_ws);
    hipLaunchKernelGGL(groupfc_norm, dim3(25600), dim3(128), 0, stream,
                       (const float*)d_ws, out);
  } else {
    hipLaunchKernelGGL(groupfc_kernel, dim3(208), dim3(512), 0, stream, h, W, out);
  }
}

// Round 8
// 214.136 us; speedup vs baseline: 1.0740x; 1.0740x over previous
//
#include <hip/hip_runtime.h>

// Problem constants: h[B,G,D], W[G,D,K], out[B,G,K]
#define Gn   100
#define Bn   256
#define Dn   768
#define Kn   128
#define LDP  40   // LDS leading dim in shorts (32+8)

// ws layout: P[4][256][100][128] bf16 @ 0 (26,214,400 B);
//            ASQ f32 [4][100][256] @ float-offset 6,553,600 (409,600 B);
//            BSQ f32 [4][100][128] @ float-offset 6,656,000 (204,800 B).
// Total 26,828,800 B. Every slot single-writer -> no zeroing needed.
#define AOFF 6553600
#define BOFF 6656000
#define PKT  3276800   // per-kt P stride (ushort elems)

typedef __attribute__((ext_vector_type(8))) short short8;
typedef __attribute__((ext_vector_type(4))) float f32x4;

// pack two fp32 -> two bf16 (round-to-nearest, ties away) in 3 VALU
__device__ inline unsigned pack2(float lo, float hi) {
  union { float f; unsigned u; } a, b; a.f = lo; b.f = hi;
  return __builtin_amdgcn_perm(b.u + 0x8000u, a.u + 0x8000u, 0x07060302u);
}

// Non-draining block barrier: execution sync + LDS-write visibility ONLY.
__device__ inline void barrier_nodrain() {
  asm volatile("s_waitcnt lgkmcnt(0)\n\ts_barrier" ::: "memory");
}

// ============================ R8 split-K path ============================
// R7 post-mortem: the 13.1M fp32 atomicAdds (WRITE_SIZE 99 MB, VALUBusy 3%)
// were the entire regression; the GEMM core passed at 84 VGPR / 43 KB LDS /
// 3 blk/CU. R8 keeps that core and replaces atomics with single-writer bf16
// partial stores (26 MB streaming) + a tiny combine kernel. Fill model:
// ~0.7 B/cyc per resident wave (R0: 13 waves -> 8.7 B/cyc/CU; R4/R6:
// 8 waves -> 6.2). 832 blocks @ 3.25/CU, 196 KB/block -> ~30 us GEMM phase.
struct SAS { float4 a0, a1, a2, a3; };
struct SBS { float2 b0, b1, b2, b3, b4, b5, b6, b7; };

__global__ __launch_bounds__(256, 3) void groupfc_splitk(
    const float* __restrict__ h, const float* __restrict__ W,
    float* __restrict__ ws) {
  // grid 832 = 13*64; xcd=id&7; q=id>>3: tk=q&7 (mt*4+kt), gh=q>>3 (0..12);
  // g=gh*8+xcd. All 8 blocks of a group land on one XCD (B re-read L2-hits).
  const int id  = blockIdx.x;
  const int xcd = id & 7;
  const int q   = id >> 3;
  const int tk  = q & 7;
  const int gh  = q >> 3;
  const int g   = gh * 8 + xcd;
  if (g >= Gn) return;                       // pad blocks exit pre-barrier
  const int mt  = tk >> 2;                   // 0..1 (rows of 128)
  const int kt  = tk & 3;                    // 0..3 (d-range of 192)

  const int t    = threadIdx.x;
  const int lane = t & 63;
  const int wave = t >> 6;                   // 0..3
  const int wm   = wave >> 1, wn = wave & 1; // 2x2 wave grid, 64x64 each
  const int l15  = lane & 15, quad = lane >> 4;

  __shared__ __align__(16) short Af[2][128 * LDP];  // [m][k] bf16
  __shared__ __align__(16) short Bf[2][128 * LDP];  // [n][k] bf16
  __shared__ float BssqL[4][128];

  f32x4 acc[4][4];
#pragma unroll
  for (int mi = 0; mi < 4; ++mi)
#pragma unroll
    for (int ni = 0; ni < 4; ++ni) acc[mi][ni] = (f32x4){0.f, 0.f, 0.f, 0.f};

  // A staging: thread -> rows ar & ar+64, 8 contiguous k at ac (2x dwordx4 ea)
  const int ar = t >> 2;                     // 0..63
  const int ac = (t & 3) * 8;
  const float* aptr  = h + ((size_t)(mt * 128 + ar) * Gn + g) * Dn + kt * 192 + ac;
  const float* aptr2 = aptr + (size_t)64 * Gn * Dn;

  // B staging: thread -> col pair c2..c2+1, 8 d-rows at bq*8 (8x dwordx2)
  const int c2 = lane * 2;                   // 0..126
  const int bq = wave;                       // 0..3
  const float* bptr = W + (size_t)g * (Dn * Kn)
                        + (size_t)(kt * 192 + bq * 8) * Kn + c2;

  const int koff = quad * 8;
  const int m0   = wm * 64 + l15;
  const int n0   = wn * 64 + l15;

  float asq0 = 0.f, asq1 = 0.f, bs0 = 0.f, bs1 = 0.f;
  SAS A;
  SBS Bs;

  auto load_set = [&](int c) {
    const int d0 = c * 32;
    A.a0 = *(const float4*)(aptr + d0);
    A.a1 = *(const float4*)(aptr + d0 + 4);
    A.a2 = *(const float4*)(aptr2 + d0);
    A.a3 = *(const float4*)(aptr2 + d0 + 4);
    const float* bp = bptr + (size_t)d0 * Kn;
    Bs.b0 = *(const float2*)(bp);
    Bs.b1 = *(const float2*)(bp + Kn);
    Bs.b2 = *(const float2*)(bp + 2 * Kn);
    Bs.b3 = *(const float2*)(bp + 3 * Kn);
    Bs.b4 = *(const float2*)(bp + 4 * Kn);
    Bs.b5 = *(const float2*)(bp + 5 * Kn);
    Bs.b6 = *(const float2*)(bp + 6 * Kn);
    Bs.b7 = *(const float2*)(bp + 7 * Kn);
  };

  auto pack_set = [&](int buf) {
    const float4 a0 = A.a0, a1 = A.a1, a2 = A.a2, a3 = A.a3;
    asq0 += a0.x*a0.x + a0.y*a0.y + a0.z*a0.z + a0.w*a0.w
          + a1.x*a1.x + a1.y*a1.y + a1.z*a1.z + a1.w*a1.w;
    asq1 += a2.x*a2.x + a2.y*a2.y + a2.z*a2.z + a2.w*a2.w
          + a3.x*a3.x + a3.y*a3.y + a3.z*a3.z + a3.w*a3.w;
    uint4 ap;
    ap.x = pack2(a0.x, a0.y); ap.y = pack2(a0.z, a0.w);
    ap.z = pack2(a1.x, a1.y); ap.w = pack2(a1.z, a1.w);
    *(uint4*)&Af[buf][ar * LDP + ac] = ap;
    ap.x = pack2(a2.x, a2.y); ap.y = pack2(a2.z, a2.w);
    ap.z = pack2(a3.x, a3.y); ap.w = pack2(a3.z, a3.w);
    *(uint4*)&Af[buf][(ar + 64) * LDP + ac] = ap;

    const float2 b0 = Bs.b0, b1 = Bs.b1, b2 = Bs.b2, b3 = Bs.b3,
                 b4 = Bs.b4, b5 = Bs.b5, b6 = Bs.b6, b7 = Bs.b7;
    bs0 += b0.x*b0.x + b1.x*b1.x + b2.x*b2.x + b3.x*b3.x
         + b4.x*b4.x + b5.x*b5.x + b6.x*b6.x + b7.x*b7.x;
    bs1 += b0.y*b0.y + b1.y*b1.y + b2.y*b2.y + b3.y*b3.y
         + b4.y*b4.y + b5.y*b5.y + b6.y*b6.y + b7.y*b7.y;
    uint4 w0, w1;
    w0.x = pack2(b0.x, b1.x); w0.y = pack2(b2.x, b3.x);
    w0.z = pack2(b4.x, b5.x); w0.w = pack2(b6.x, b7.x);
    w1.x = pack2(b0.y, b1.y); w1.y = pack2(b2.y, b3.y);
    w1.z = pack2(b4.y, b5.y); w1.w = pack2(b6.y, b7.y);
    *(uint4*)&Bf[buf][c2 * LDP + bq * 8]       = w0;
    *(uint4*)&Bf[buf][(c2 + 1) * LDP + bq * 8] = w1;
  };

  auto mfma_step = [&](int buf) {
    short8 af[4], bf[4];
#pragma unroll
    for (int mi = 0; mi < 4; ++mi)
      af[mi] = *(const short8*)&Af[buf][(m0 + mi * 16) * LDP + koff];
#pragma unroll
    for (int ni = 0; ni < 4; ++ni)
      bf[ni] = *(const short8*)&Bf[buf][(n0 + ni * 16) * LDP + koff];
#pragma unroll
    for (int mi = 0; mi < 4; ++mi)
#pragma unroll
      for (int ni = 0; ni < 4; ++ni)
        acc[mi][ni] = __builtin_amdgcn_mfma_f32_16x16x32_bf16(
            af[mi], bf[ni], acc[mi][ni], 0, 0, 0);
  };

  // ---- 6 chunks of 32; 2 LDS buffers (schedule proven in R7) ----
  load_set(0);
  pack_set(0);
  load_set(1); barrier_nodrain(); mfma_step(0); pack_set(1);
  load_set(2); barrier_nodrain(); mfma_step(1); pack_set(0);
  load_set(3); barrier_nodrain(); mfma_step(0); pack_set(1);
  load_set(4); barrier_nodrain(); mfma_step(1); pack_set(0);
  load_set(5); barrier_nodrain(); mfma_step(0); pack_set(1);
               barrier_nodrain(); mfma_step(1);

  // ---- ssq partials -> ws (single writer per slot) ----
  asq0 += __shfl_xor(asq0, 1); asq0 += __shfl_xor(asq0, 2);
  asq1 += __shfl_xor(asq1, 1); asq1 += __shfl_xor(asq1, 2);
  if ((t & 3) == 0) {                        // A[row,d-slice] touched by ONE block
    ws[AOFF + kt * 25600 + g * 256 + mt * 128 + ar]      = asq0;
    ws[AOFF + kt * 25600 + g * 256 + mt * 128 + ar + 64] = asq1;
  }
  BssqL[bq][c2]     = bs0;                   // B read by both mt blocks:
  BssqL[bq][c2 + 1] = bs1;                   // only mt==0 contributes
  __syncthreads();
  if (mt == 0 && t < 128) {
    const float bsum = BssqL[0][t] + BssqL[1][t] + BssqL[2][t] + BssqL[3][t];
    ws[BOFF + kt * 12800 + g * 128 + t] = bsum;
  }

  // ---- partial dots -> bf16 stores (single writer; replaces R7 atomics) ----
  // C/D layout: col = lane&15, row = quad*4 + reg
  unsigned short* P = (unsigned short*)ws;
  const size_t ktP = (size_t)kt * PKT;
#pragma unroll
  for (int mi = 0; mi < 4; ++mi) {
#pragma unroll
    for (int r = 0; r < 4; ++r) {
      const int grow = mt * 128 + wm * 64 + mi * 16 + quad * 4 + r;
      const size_t rb = ktP + ((size_t)grow * Gn + g) * Kn;
#pragma unroll
      for (int ni = 0; ni < 4; ++ni) {
        union { float f; unsigned u; } cv; cv.f = acc[mi][ni][r];
        P[rb + wn * 64 + ni * 16 + l15] = (unsigned short)((cv.u + 0x8000u) >> 16);
      }
    }
  }
}

// combine: out[b,g,c] = (sum_kt P[kt]) / (max(||h_row||,eps)*max(||w_col||,eps))
__global__ __launch_bounds__(256) void groupfc_combine(
    const float* __restrict__ wsf, float* __restrict__ out) {
  const int i   = blockIdx.x * 256 + threadIdx.x;  // 0..409599 (exact)
  const int b   = i / 1600;                  // 1600 = 100 g * 16 col-chunks
  const int rem = i - b * 1600;
  const int g   = rem >> 4;
  const int c0  = (rem & 15) * 8;

  const float as = wsf[AOFF + g * 256 + b]         + wsf[AOFF + 25600 + g * 256 + b]
                 + wsf[AOFF + 51200 + g * 256 + b] + wsf[AOFF + 76800 + g * 256 + b];
  const float hs = 1.0f / fmaxf(sqrtf(as), 1e-12f);

  float4 bl = {0.f,0.f,0.f,0.f}, bh = {0.f,0.f,0.f,0.f};
#pragma unroll
  for (int kt = 0; kt < 4; ++kt) {
    const float4 x = *(const float4*)&wsf[BOFF + kt * 12800 + g * 128 + c0];
    const float4 y = *(const float4*)&wsf[BOFF + kt * 12800 + g * 128 + c0 + 4];
    bl.x += x.x; bl.y += x.y; bl.z += x.z; bl.w += x.w;
    bh.x += y.x; bh.y += y.y; bh.z += y.z; bh.w += y.w;
  }

  const unsigned short* P = (const unsigned short*)wsf;
  const size_t base = ((size_t)b * Gn + g) * Kn + c0;
  const short8 p0 = *(const short8*)&P[base];
  const short8 p1 = *(const short8*)&P[base + PKT];
  const short8 p2 = *(const short8*)&P[base + 2 * (size_t)PKT];
  const short8 p3 = *(const short8*)&P[base + 3 * (size_t)PKT];

  float r[8];
#pragma unroll
  for (int jj = 0; jj < 8; ++jj) {
    union { unsigned u; float f; } v0, v1, v2, v3;
    v0.u = ((unsigned)(unsigned short)p0[jj]) << 16;
    v1.u = ((unsigned)(unsigned short)p1[jj]) << 16;
    v2.u = ((unsigned)(unsigned short)p2[jj]) << 16;
    v3.u = ((unsigned)(unsigned short)p3[jj]) << 16;
    r[jj] = (v0.f + v1.f) + (v2.f + v3.f);
  }
  const float wc[8] = {bl.x, bl.y, bl.z, bl.w, bh.x, bh.y, bh.z, bh.w};
  float4 o0, o1;
  o0.x = r[0] * hs * (1.0f / fmaxf(sqrtf(wc[0]), 1e-12f));
  o0.y = r[1] * hs * (1.0f / fmaxf(sqrtf(wc[1]), 1e-12f));
  o0.z = r[2] * hs * (1.0f / fmaxf(sqrtf(wc[2]), 1e-12f));
  o0.w = r[3] * hs * (1.0f / fmaxf(sqrtf(wc[3]), 1e-12f));
  o1.x = r[4] * hs * (1.0f / fmaxf(sqrtf(wc[4]), 1e-12f));
  o1.y = r[5] * hs * (1.0f / fmaxf(sqrtf(wc[5]), 1e-12f));
  o1.z = r[6] * hs * (1.0f / fmaxf(sqrtf(wc[6]), 1e-12f));
  o1.w = r[7] * hs * (1.0f / fmaxf(sqrtf(wc[7]), 1e-12f));
  *(float4*)&out[base]     = o0;
  *(float4*)&out[base + 4] = o1;
}

// ===================== R6 fallback (ws too small) =======================
__device__ inline void gload16(const float* g, float* l) {
  __builtin_amdgcn_global_load_lds(
      (const __attribute__((address_space(1))) void*)g,
      (__attribute__((address_space(3))) void*)l, 16, 0, 0);
}

__global__ __launch_bounds__(512, 2) void groupfc_kernel(
    const float* __restrict__ h, const float* __restrict__ W,
    float* __restrict__ out) {
  const int id  = blockIdx.x;
  const int xcd = id & 7;
  const int j   = id >> 3;
  const int mt  = j & 1;
  const int g   = xcd + (j >> 1) * 8;
  if (g >= Gn) return;

  const int t    = threadIdx.x;
  const int lane = t & 63;
  const int w    = t >> 6;
  const int wm   = w >> 2;
  const int wn   = w & 3;
  const int l15  = lane & 15, quad = lane >> 4;

  __shared__ __align__(16) float Af[4][128 * 32];
  __shared__ __align__(16) float Bf[4][32 * 128];
  __shared__ float AssqL[128];
  __shared__ float BssqL[128];

  f32x4 acc[4][2];
#pragma unroll
  for (int mi = 0; mi < 4; ++mi)
#pragma unroll
    for (int ni = 0; ni < 2; ++ni) acc[mi][ni] = (f32x4){0.f, 0.f, 0.f, 0.f};

  const int arow0 = w * 16 + (lane >> 3);
  const int axor  = (lane & 7) ^ ((lane >> 3) & 7);
  const float* asrc0 = h + ((size_t)(mt * 128 + arow0) * Gn + g) * Dn + 4 * axor;
  const float* asrc1 = h + ((size_t)(mt * 128 + arow0 + 8) * Gn + g) * Dn + 4 * axor;
  const float* Wg = W + (size_t)g * (Dn * Kn);
  const int dd0 = w * 4 + (lane >> 5);
  const int dd1 = dd0 + 2;
  const float* bsrc0 = Wg + (size_t)dd0 * Kn + 4 * ((lane & 31) ^ ((dd0 >> 3) << 2));
  const float* bsrc1 = Wg + (size_t)dd1 * Kn + 4 * ((lane & 31) ^ ((dd1 >> 3) << 2));
  const int ldsq = w * 512;

  auto issue = [&](int tile, float* AbW, float* BbW) {
    const size_t ad = (size_t)tile * 32;
    const size_t bd = (size_t)tile * 32 * Kn;
    gload16(asrc0 + ad, AbW + ldsq);
    gload16(asrc1 + ad, AbW + ldsq + 256);
    gload16(bsrc0 + bd, BbW + ldsq);
    gload16(bsrc1 + bd, BbW + ldsq + 256);
  };

  const int aBase = (wm * 64 + l15) * 32;
  const int ac0   = ((quad * 2) ^ (l15 & 7)) * 4;
  const int ac1   = ((quad * 2 + 1) ^ (l15 & 7)) * 4;
  const int col0 = wn * 32 + l15;
  const int col1 = col0 + 16;
  const int b0   = quad * 1024 + (((col0 >> 2) ^ (quad << 2)) << 2) + (l15 & 3);
  const int b1   = quad * 1024 + (((col1 >> 2) ^ (quad << 2)) << 2) + (l15 & 3);

  float asq[4] = {0.f, 0.f, 0.f, 0.f};
  float bsq[2] = {0.f, 0.f};

  auto compute = [&](const float* Ab, const float* Bb) {
    short8 af[4], bf[2];
#pragma unroll
    for (int mi = 0; mi < 4; ++mi) {
      const f32x4 x0 = *(const f32x4*)&Ab[aBase + mi * 512 + ac0];
      const f32x4 x1 = *(const f32x4*)&Ab[aBase + mi * 512 + ac1];
      union { uint4 u; short8 s; } r;
      r.u.x = pack2(x0.x, x0.y); r.u.y = pack2(x0.z, x0.w);
      r.u.z = pack2(x1.x, x1.y); r.u.w = pack2(x1.z, x1.w);
      af[mi] = r.s;
      if (wn == 0)
        asq[mi] += x0.x*x0.x + x0.y*x0.y + x0.z*x0.z + x0.w*x0.w
                 + x1.x*x1.x + x1.y*x1.y + x1.z*x1.z + x1.w*x1.w;
    }
#pragma unroll
    for (int ni = 0; ni < 2; ++ni) {
      const int bb = ni ? b1 : b0;
      float z0 = Bb[bb],           z1 = Bb[bb + 128],
            z2 = Bb[bb + 2 * 128], z3 = Bb[bb + 3 * 128],
            z4 = Bb[bb + 4 * 128], z5 = Bb[bb + 5 * 128],
            z6 = Bb[bb + 6 * 128], z7 = Bb[bb + 7 * 128];
      union { uint4 u; short8 s; } r;
      r.u.x = pack2(z0, z1); r.u.y = pack2(z2, z3);
      r.u.z = pack2(z4, z5); r.u.w = pack2(z6, z7);
      bf[ni] = r.s;
      if (wm == 0)
        bsq[ni] += z0*z0 + z1*z1 + z2*z2 + z3*z3 + z4*z4 + z5*z5 + z6*z6 + z7*z7;
    }
#pragma unroll
    for (int mi = 0; mi < 4; ++mi)
#pragma unroll
      for (int ni = 0; ni < 2; ++ni)
        acc[mi][ni] = __builtin_amdgcn_mfma_f32_16x16x32_bf16(
            af[mi], bf[ni], acc[mi][ni], 0, 0, 0);
  };

#define VMW(N) asm volatile("s_waitcnt vmcnt(" #N ")" ::: "memory")
#define BAR()  asm volatile("s_barrier" ::: "memory")

  issue(0, Af[0], Bf[0]);
  issue(1, Af[1], Bf[1]);

  for (int tt = 0; tt < 20; tt += 4) {
    issue(tt + 2, Af[2], Bf[2]); VMW(8); BAR(); compute(Af[0], Bf[0]);
    issue(tt + 3, Af[3], Bf[3]); VMW(8); BAR(); compute(Af[1], Bf[1]);
    issue(tt + 4, Af[0], Bf[0]); VMW(8); BAR(); compute(Af[2], Bf[2]);
    issue(tt + 5, Af[1], Bf[1]); VMW(8); BAR(); compute(Af[3], Bf[3]);
  }
  issue(22, Af[2], Bf[2]); VMW(8); BAR(); compute(Af[0], Bf[0]);
  issue(23, Af[3], Bf[3]); VMW(8); BAR(); compute(Af[1], Bf[1]);
  VMW(4); BAR(); compute(Af[2], Bf[2]);
  VMW(0); BAR(); compute(Af[3], Bf[3]);

#undef VMW
#undef BAR

  if (wn == 0) {
#pragma unroll
    for (int mi = 0; mi < 4; ++mi) {
      asq[mi] += __shfl_xor(asq[mi], 16);
      asq[mi] += __shfl_xor(asq[mi], 32);
      if (quad == 0) AssqL[wm * 64 + mi * 16 + l15] = asq[mi];
    }
  }
  if (wm == 0) {
#pragma unroll
    for (int ni = 0; ni < 2; ++ni) {
      bsq[ni] += __shfl_xor(bsq[ni], 16);
      bsq[ni] += __shfl_xor(bsq[ni], 32);
      if (quad == 0) BssqL[wn * 32 + ni * 16 + l15] = bsq[ni];
    }
  }
  __syncthreads();

  const float wi0 = 1.0f / fmaxf(sqrtf(BssqL[col0]), 1e-12f);
  const float wi1 = 1.0f / fmaxf(sqrtf(BssqL[col1]), 1e-12f);

#pragma unroll
  for (int mi = 0; mi < 4; ++mi) {
#pragma unroll
    for (int r = 0; r < 4; ++r) {
      const int lr = wm * 64 + mi * 16 + quad * 4 + r;
      const float hs = 1.0f / fmaxf(sqrtf(AssqL[lr]), 1e-12f);
      const int row = mt * 128 + lr;
      const size_t ob = ((size_t)row * Gn + g) * Kn;
      out[ob + col0] = acc[mi][0][r] * hs * wi0;
      out[ob + col1] = acc[mi][1][r] * hs * wi1;
    }
  }
}

extern "C" void kernel_launch(void* const* d_in, const int* in_sizes, int n_in,
                              void* d_out, int out_size, void* d_ws, size_t ws_size,
                              hipStream_t stream) {
  const float* h = (const float*)d_in[0];          // [B,G,D]
  const float* W = (const float*)d_in[1];          // [G,D,K]
  float* out = (float*)d_out;                      // [B,G,K]
  if (d_ws && ws_size >= 26828800) {
    hipLaunchKernelGGL(groupfc_splitk, dim3(832), dim3(256), 0, stream,
                       h, W, (float*)d_ws);
    hipLaunchKernelGGL(groupfc_combine, dim3(1600), dim3(256), 0, stream,
                       (const float*)d_ws, out);
  } else {
    hipLaunchKernelGGL(groupfc_kernel, dim3(208), dim3(512), 0, stream, h, W, out);
  }
}

// Round 9
// 171.381 us; speedup vs baseline: 1.3419x; 1.2495x over previous
//
#include <hip/hip_runtime.h>

// Problem constants: h[B,G,D], W[G,D,K], out[B,G,K]
#define Gn   100
#define Bn   256
#define Dn   768
#define Kn   128

typedef __attribute__((ext_vector_type(8))) short short8;
typedef __attribute__((ext_vector_type(4))) float f32x4;

// pack two fp32 -> two bf16 (round-to-nearest, ties away) in 3 VALU
__device__ inline unsigned pack2(float lo, float hi) {
  union { float f; unsigned u; } a, b; a.f = lo; b.f = hi;
  return __builtin_amdgcn_perm(b.u + 0x8000u, a.u + 0x8000u, 0x07060302u);
}

// Async global->LDS DMA, 16B per lane. LDS dest wave-uniform base + lane*16.
__device__ inline void gload16(const float* g, float* l) {
  __builtin_amdgcn_global_load_lds(
      (const __attribute__((address_space(1))) void*)g,
      (__attribute__((address_space(3))) void*)l, 16, 0, 0);
}

// R9: R0 geometry x R6 staging. 64x64 tiles, 832 blocks (8 tiles/group pinned
// to one XCD -> B x4 / A x2 re-reads are L2-hits), 4 waves/block, 2 blocks/CU
// co-resident (64 KB LDS) = two independent barrier domains per CU.
// Staging is pure global_load_lds_dwordx4 of RAW FP32 (m97's high-rate
// mechanism; R6's verified 4-buffer + vmcnt(8) schedule), bf16 convert at
// fragment-build. Evidence: fill rate is source/load-quality-dependent, not
// a HW wall (R0 8.7 B/cyc/CU w/ scalar loads+L2 reuse; R6 6.2 w/ DMA but no
// L2 reuse; m97 21 w/ DMA + L2-heavy source). This combines all three wins.
// Both-sides swizzle (rule 21): linear LDS dest, inverse-swizzled GLOBAL src,
// swizzled read. A[64][32]: chunk ^= row&7. B[32][64]: chunk ^= (k>>3)<<2.
__global__ __launch_bounds__(256, 2) void groupfc_kernel(
    const float* __restrict__ h, const float* __restrict__ W,
    float* __restrict__ out) {
  // grid 832 = 104*8; decode: xcd=id%8 -> g%8, tile=(id>>3)%8 (R0's proven map)
  const int id   = blockIdx.x;
  const int xcd  = id & 7;
  const int rest = id >> 3;
  const int tl   = rest & 7;
  const int g    = (rest >> 3) * 8 + xcd;
  if (g >= Gn) return;                       // pad blocks exit before any barrier
  const int mt   = tl >> 1;                  // 0..3 (rows of 64)
  const int nt   = tl & 1;                   // 0..1 (cols of 64)

  const int t    = threadIdx.x;
  const int lane = t & 63;
  const int w    = t >> 6;                   // wave 0..3
  const int wm   = w >> 1, wn = w & 1;       // 2x2 wave grid, 32x32 each
  const int l15  = lane & 15, quad = lane >> 4;

  // 4 buffers x (A 8KB + B 8KB) fp32 = 64 KB; + norms 512 B.
  __shared__ __align__(16) float Af[4][64 * 32];   // [row][kchunk swz] fp32
  __shared__ __align__(16) float Bf[4][32 * 64];   // [k][colchunk swz] fp32
  __shared__ float AssqL[64];
  __shared__ float BssqL[64];

  f32x4 acc[2][2];
#pragma unroll
  for (int mi = 0; mi < 2; ++mi)
#pragma unroll
    for (int ni = 0; ni < 2; ++ni) acc[mi][ni] = (f32x4){0.f, 0.f, 0.f, 0.f};

  // ---- DMA staging setup ----
  // A call q in {0,1}: dest row r = q*32 + w*8 + (lane>>3), chunk lane&7
  //   (dest floats: q*1024 + w*256 + lane*4). Source k-chunk = (lane&7)^(r&7);
  //   r&7 == lane>>3 for both q (32%8==0).
  const int ar0  = w * 8 + (lane >> 3);
  const int aswz = (lane & 7) ^ (lane >> 3);
  const float* asrc0 = h + ((size_t)(mt * 64 + ar0) * Gn + g) * Dn + 4 * aswz;
  const float* asrc1 = h + ((size_t)(mt * 64 + ar0 + 32) * Gn + g) * Dn + 4 * aswz;
  // B call q: dest k = q*16 + w*4 + (lane>>4), chunk lane&15.
  //   Source col-chunk = (lane&15) ^ ((k>>3)<<2).
  const float* Wg = W + (size_t)g * (Dn * Kn);
  const int bk0 = w * 4 + (lane >> 4);
  const int bk1 = bk0 + 16;
  const float* bsrc0 = Wg + (size_t)bk0 * Kn + nt * 64 + 4 * ((lane & 15) ^ ((bk0 >> 3) << 2));
  const float* bsrc1 = Wg + (size_t)bk1 * Kn + nt * 64 + 4 * ((lane & 15) ^ ((bk1 >> 3) << 2));
  const int ldsq = w * 256;                  // per-wave float base (q0); q1 +1024

  auto issue = [&](int tile, float* Ab, float* Bb) {
    const size_t ad = (size_t)tile * 32;
    const size_t bd = (size_t)tile * 32 * Kn;
    gload16(asrc0 + ad, Ab + ldsq);
    gload16(asrc1 + ad, Ab + ldsq + 1024);
    gload16(bsrc0 + bd, Bb + ldsq);
    gload16(bsrc1 + bd, Bb + ldsq + 1024);
  };

  // ---- fragment read addressing (swizzled; 2-way max bank aliasing) ----
  // A frag (mi,i): row r = wm*32 + mi*16 + l15, kchunk = (quad*2+i)^(r&7)
  const int arm0 = wm * 32 + l15;
  // B frag (ni,j): k = quad*8+j, col = wn*32+ni*16+l15:
  //   float idx = k*64 + ((col>>2)^(quad<<2))*4 + (col&3)
  const int col0 = wn * 32 + l15;
  const int col1 = col0 + 16;
  const int bb0  = (((col0 >> 2) ^ (quad << 2)) << 2) + (col0 & 3);
  const int bb1  = (((col1 >> 2) ^ (quad << 2)) << 2) + (col1 & 3);

  float asq[2] = {0.f, 0.f};
  float bsq[2] = {0.f, 0.f};

  auto compute = [&](const float* Ab, const float* Bb) {
    short8 af[2], bf[2];
#pragma unroll
    for (int mi = 0; mi < 2; ++mi) {
      const int r = arm0 + mi * 16;
      const f32x4 x0 = *(const f32x4*)&Ab[r * 32 + (((quad * 2)     ^ (r & 7)) << 2)];
      const f32x4 x1 = *(const f32x4*)&Ab[r * 32 + (((quad * 2 + 1) ^ (r & 7)) << 2)];
      union { uint4 u; short8 s; } rr;
      rr.u.x = pack2(x0.x, x0.y); rr.u.y = pack2(x0.z, x0.w);
      rr.u.z = pack2(x1.x, x1.y); rr.u.w = pack2(x1.z, x1.w);
      af[mi] = rr.s;
      if (wn == 0)
        asq[mi] += x0.x*x0.x + x0.y*x0.y + x0.z*x0.z + x0.w*x0.w
                 + x1.x*x1.x + x1.y*x1.y + x1.z*x1.z + x1.w*x1.w;
    }
#pragma unroll
    for (int ni = 0; ni < 2; ++ni) {
      const float* bp = Bb + quad * 512 + (ni ? bb1 : bb0);   // k = quad*8
      const float z0 = bp[0],       z1 = bp[64],      z2 = bp[2 * 64],
                  z3 = bp[3 * 64],  z4 = bp[4 * 64],  z5 = bp[5 * 64],
                  z6 = bp[6 * 64],  z7 = bp[7 * 64];
      union { uint4 u; short8 s; } rr;
      rr.u.x = pack2(z0, z1); rr.u.y = pack2(z2, z3);
      rr.u.z = pack2(z4, z5); rr.u.w = pack2(z6, z7);
      bf[ni] = rr.s;
      if (wm == 0)
        bsq[ni] += z0*z0 + z1*z1 + z2*z2 + z3*z3 + z4*z4 + z5*z5 + z6*z6 + z7*z7;
    }
#pragma unroll
    for (int mi = 0; mi < 2; ++mi)
#pragma unroll
      for (int ni = 0; ni < 2; ++ni)
        acc[mi][ni] = __builtin_amdgcn_mfma_f32_16x16x32_bf16(
            af[mi], bf[ni], acc[mi][ni], 0, 0, 0);
  };

#define VMW(N) asm volatile("s_waitcnt vmcnt(" #N ")" ::: "memory")
#define BAR()  asm volatile("s_barrier" ::: "memory")

  // ---- prologue: tiles 0,1 in flight ----
  issue(0, Af[0], Bf[0]);
  issue(1, Af[1], Bf[1]);

  // ---- main loop (R6's verified schedule): iter t reads buf t%4, issues
  // tile t+2 -> buf (t+2)%4. vmcnt(8): tiles t+1,t+2 (4 calls each) may stay
  // in flight; tile t complete. Barrier after the wait publishes ALL waves'
  // DMA completions before any wave reads the buffer.
  for (int tt = 0; tt < 20; tt += 4) {
    issue(tt + 2, Af[2], Bf[2]); VMW(8); BAR(); compute(Af[0], Bf[0]);
    issue(tt + 3, Af[3], Bf[3]); VMW(8); BAR(); compute(Af[1], Bf[1]);
    issue(tt + 4, Af[0], Bf[0]); VMW(8); BAR(); compute(Af[2], Bf[2]);
    issue(tt + 5, Af[1], Bf[1]); VMW(8); BAR(); compute(Af[3], Bf[3]);
  }
  issue(22, Af[2], Bf[2]); VMW(8); BAR(); compute(Af[0], Bf[0]);
  issue(23, Af[3], Bf[3]); VMW(8); BAR(); compute(Af[1], Bf[1]);
  VMW(4); BAR(); compute(Af[2], Bf[2]);
  VMW(0); BAR(); compute(Af[3], Bf[3]);

#undef VMW
#undef BAR

  // ---- norm reduction (ssq accumulated on fragment reads, once per elem) ----
  if (wn == 0) {                             // waves 0,2: A rows wm*32..+31
#pragma unroll
    for (int mi = 0; mi < 2; ++mi) {
      asq[mi] += __shfl_xor(asq[mi], 16);
      asq[mi] += __shfl_xor(asq[mi], 32);
      if (quad == 0) AssqL[wm * 32 + mi * 16 + l15] = asq[mi];
    }
  }
  if (wm == 0) {                             // waves 0,1: B cols wn*32..+31
#pragma unroll
    for (int ni = 0; ni < 2; ++ni) {
      bsq[ni] += __shfl_xor(bsq[ni], 16);
      bsq[ni] += __shfl_xor(bsq[ni], 32);
      if (quad == 0) BssqL[wn * 32 + ni * 16 + l15] = bsq[ni];
    }
  }
  __syncthreads();                           // one draining barrier: loop done

  // ---- epilogue: scale by 1/max(||h_row||,eps) * 1/max(||w_col||,eps) ----
  // C/D layout: col = lane&15, row = quad*4 + reg
  const float wi0 = 1.0f / fmaxf(sqrtf(BssqL[col0]), 1e-12f);
  const float wi1 = 1.0f / fmaxf(sqrtf(BssqL[col1]), 1e-12f);

#pragma unroll
  for (int mi = 0; mi < 2; ++mi) {
#pragma unroll
    for (int r = 0; r < 4; ++r) {
      const int lr = wm * 32 + mi * 16 + quad * 4 + r;   // local row in tile
      const float hs = 1.0f / fmaxf(sqrtf(AssqL[lr]), 1e-12f);
      const int row = mt * 64 + lr;
      const size_t ob = ((size_t)row * Gn + g) * Kn + nt * 64;
      out[ob + col0] = acc[mi][0][r] * hs * wi0;
      out[ob + col1] = acc[mi][1][r] * hs * wi1;
    }
  }
}

extern "C" void kernel_launch(void* const* d_in, const int* in_sizes, int n_in,
                              void* d_out, int out_size, void* d_ws, size_t ws_size,
                              hipStream_t stream) {
  const float* h = (const float*)d_in[0];          // [B,G,D]
  const float* W = (const float*)d_in[1];          // [G,D,K]
  float* out = (float*)d_out;                      // [B,G,K]
  hipLaunchKernelGGL(groupfc_kernel, dim3(832), dim3(256), 0, stream, h, W, out);
}

// Round 10
// 165.855 us; speedup vs baseline: 1.3866x; 1.0333x over previous
//
#include <hip/hip_runtime.h>

// Problem constants: h[B,G,D], W[G,D,K], out[B,G,K]
#define Gn   100
#define Bn   256
#define Dn   768
#define Kn   128

typedef __attribute__((ext_vector_type(8))) short short8;
typedef __attribute__((ext_vector_type(4))) float f32x4;

// pack two fp32 -> two bf16 (round-to-nearest, ties away) in 3 VALU
__device__ inline unsigned pack2(float lo, float hi) {
  union { float f; unsigned u; } a, b; a.f = lo; b.f = hi;
  return __builtin_amdgcn_perm(b.u + 0x8000u, a.u + 0x8000u, 0x07060302u);
}

// Async global->LDS DMA, 16B per lane. LDS dest wave-uniform base + lane*16.
__device__ inline void gload16(const float* g, float* l) {
  __builtin_amdgcn_global_load_lds(
      (const __attribute__((address_space(1))) void*)g,
      (__attribute__((address_space(3))) void*)l, 16, 0, 0);
}

// R10: the untested Pareto point {236 MB traffic, 2 domains/CU}.
// Rate model from R0/R6/R9: per-CU L3-fill = ~6 B/cyc with 1 block-domain,
// ~8.5-8.7 with 2-3.25 domains, invariant to staging mechanism and depth.
// 157 MB config admits only 200 blocks (1 domain -> 54 us observed);
// 314 MB admits 800 (3 domains -> 58 us). This round: 128x64 tiles ->
// 416 blocks (4 tiles/group, XCD-pinned -> A/B re-reads L2-hit), 236 MB,
// 73 KB LDS -> 2 co-resident blocks/CU. Staging/swizzles verbatim from
// R6/R9 (proven): linear LDS dest + inverse-swizzled global src + swizzled
// read. 3-buffer ring, issue-after-barrier (race-safe: slot t+2 = t-1 mod 3
// rewritten only after BAR(t) > all waves' compute(t-1)), counted vmcnt(3).
__global__ __launch_bounds__(512, 4) void groupfc_kernel(
    const float* __restrict__ h, const float* __restrict__ W,
    float* __restrict__ out) {
  // grid 416 = 8*52; xcd=id&7; rest=id>>3: tl=rest&3, g=(rest>>2)*8+xcd.
  // A group's 4 tiles are consecutive in dispatch on one XCD.
  const int id   = blockIdx.x;
  const int xcd  = id & 7;
  const int rest = id >> 3;                  // 0..51
  const int tl   = rest & 3;
  const int g    = (rest >> 2) * 8 + xcd;    // 0..103
  if (g >= Gn) return;                       // pad blocks exit before any barrier
  const int mt   = tl >> 1;                  // 0..1 (rows of 128)
  const int ntc  = tl & 1;                   // 0..1 (cols of 64)

  const int t    = threadIdx.x;
  const int lane = t & 63;
  const int w    = t >> 6;                   // wave 0..7
  const int wm   = w >> 1;                   // 0..3 (32-row strips)
  const int wn   = w & 1;                    // 0..1 (32-col strips)
  const int l15  = lane & 15, quad = lane >> 4;

  // 3 buffers x (A 16KB + B 8KB) fp32 = 72 KB; + norms 768 B.
  __shared__ __align__(16) float Af[3][128 * 32];  // [row][kchunk swz] fp32
  __shared__ __align__(16) float Bf[3][32 * 64];   // [k][colchunk swz] fp32
  __shared__ float AssqL[128];
  __shared__ float BssqL[64];

  f32x4 acc[2][2];
#pragma unroll
  for (int mi = 0; mi < 2; ++mi)
#pragma unroll
    for (int ni = 0; ni < 2; ++ni) acc[mi][ni] = (f32x4){0.f, 0.f, 0.f, 0.f};

  // ---- DMA staging setup ----
  // A call q in {0,1}: dest row r = w*16 + q*8 + (lane>>3), chunk lane&7
  //   (dest floats: w*512 + q*256 + lane*4). Src k-chunk = (lane&7)^(r&7);
  //   r&7 == lane>>3 for both q.
  const int ar   = w * 16 + (lane >> 3);
  const int aswz = (lane & 7) ^ (lane >> 3);
  const float* asrc0 = h + ((size_t)(mt * 128 + ar) * Gn + g) * Dn + 4 * aswz;
  const float* asrc1 = asrc0 + (size_t)8 * Gn * Dn;      // rows +8
  // B: one call/wave: k = w*4 + (lane>>4), chunk = lane&15 (dest w*256+lane*4).
  //   Src col-chunk = (lane&15) ^ ((k>>3)<<2).
  const float* Wg = W + (size_t)g * (Dn * Kn);
  const int bk = w * 4 + (lane >> 4);                    // 0..31
  const float* bsrc = Wg + (size_t)bk * Kn + ntc * 64
                         + 4 * ((lane & 15) ^ ((bk >> 3) << 2));
  const int adst = w * 512;                  // A dest float base (q0); q1 +256
  const int bdst = w * 256;

  auto issue = [&](int tile, float* Ab, float* Bb) {
    const size_t ad = (size_t)tile * 32;
    const size_t bd = (size_t)tile * 32 * Kn;
    gload16(asrc0 + ad, Ab + adst);
    gload16(asrc1 + ad, Ab + adst + 256);
    gload16(bsrc + bd, Bb + bdst);
  };

  // ---- fragment read addressing (swizzled; 2-way max bank aliasing) ----
  const int col0 = wn * 32 + l15;            // + ni*16

  float asq[2] = {0.f, 0.f};
  float bsq[2] = {0.f, 0.f};

  auto compute = [&](const float* Ab, const float* Bb) {
    short8 af[2], bf[2];
#pragma unroll
    for (int mi = 0; mi < 2; ++mi) {
      const int r = wm * 32 + mi * 16 + l15;
      const f32x4 x0 = *(const f32x4*)&Ab[r * 32 + (((quad * 2)     ^ (l15 & 7)) << 2)];
      const f32x4 x1 = *(const f32x4*)&Ab[r * 32 + (((quad * 2 + 1) ^ (l15 & 7)) << 2)];
      union { uint4 u; short8 s; } rr;
      rr.u.x = pack2(x0.x, x0.y); rr.u.y = pack2(x0.z, x0.w);
      rr.u.z = pack2(x1.x, x1.y); rr.u.w = pack2(x1.z, x1.w);
      af[mi] = rr.s;
      if (wn == 0)
        asq[mi] += x0.x*x0.x + x0.y*x0.y + x0.z*x0.z + x0.w*x0.w
                 + x1.x*x1.x + x1.y*x1.y + x1.z*x1.z + x1.w*x1.w;
    }
#pragma unroll
    for (int ni = 0; ni < 2; ++ni) {
      const int c = col0 + ni * 16;
      const float* bp = Bb + quad * 512 + (((c >> 2) ^ (quad << 2)) << 2) + (c & 3);
      const float z0 = bp[0],       z1 = bp[64],      z2 = bp[2 * 64],
                  z3 = bp[3 * 64],  z4 = bp[4 * 64],  z5 = bp[5 * 64],
                  z6 = bp[6 * 64],  z7 = bp[7 * 64];
      union { uint4 u; short8 s; } rr;
      rr.u.x = pack2(z0, z1); rr.u.y = pack2(z2, z3);
      rr.u.z = pack2(z4, z5); rr.u.w = pack2(z6, z7);
      bf[ni] = rr.s;
      if (wm == 0)
        bsq[ni] += z0*z0 + z1*z1 + z2*z2 + z3*z3 + z4*z4 + z5*z5 + z6*z6 + z7*z7;
    }
#pragma unroll
    for (int mi = 0; mi < 2; ++mi)
#pragma unroll
      for (int ni = 0; ni < 2; ++ni)
        acc[mi][ni] = __builtin_amdgcn_mfma_f32_16x16x32_bf16(
            af[mi], bf[ni], acc[mi][ni], 0, 0, 0);
  };

#define VMW(N) asm volatile("s_waitcnt vmcnt(" #N ")" ::: "memory")
#define BAR()  asm volatile("s_barrier" ::: "memory")

  // ---- prologue: tiles 0,1 in flight ----
  issue(0, Af[0], Bf[0]);
  issue(1, Af[1], Bf[1]);

  // ---- main loop: 24 K-steps. Iter t: VMW(3) (tile t complete, t+1's 3
  // calls may fly) -> BAR (publish all waves' DMA) -> issue tile t+2 into
  // slot (t+2)%3 == (t-1)%3 (safe: all compute(t-1) finished before BAR(t))
  // -> compute slot t%3.
  for (int c = 0; c < 21; c += 3) {
    VMW(3); BAR(); issue(c + 2, Af[2], Bf[2]); compute(Af[0], Bf[0]);
    VMW(3); BAR(); issue(c + 3, Af[0], Bf[0]); compute(Af[1], Bf[1]);
    VMW(3); BAR(); issue(c + 4, Af[1], Bf[1]); compute(Af[2], Bf[2]);
  }
  // tail: t = 21,22,23 (tile 23 issued at t=21; then drain)
  VMW(3); BAR(); issue(23, Af[2], Bf[2]); compute(Af[0], Bf[0]);
  VMW(3); BAR(); compute(Af[1], Bf[1]);
  VMW(0); BAR(); compute(Af[2], Bf[2]);

#undef VMW
#undef BAR

  // ---- norm reduction (ssq accumulated on fragment reads, once per elem) ----
  if (wn == 0) {                             // waves 0,2,4,6: rows wm*32..+31
#pragma unroll
    for (int mi = 0; mi < 2; ++mi) {
      asq[mi] += __shfl_xor(asq[mi], 16);
      asq[mi] += __shfl_xor(asq[mi], 32);
      if (quad == 0) AssqL[wm * 32 + mi * 16 + l15] = asq[mi];
    }
  }
  if (wm == 0) {                             // waves 0,1: cols wn*32..+31
#pragma unroll
    for (int ni = 0; ni < 2; ++ni) {
      bsq[ni] += __shfl_xor(bsq[ni], 16);
      bsq[ni] += __shfl_xor(bsq[ni], 32);
      if (quad == 0) BssqL[wn * 32 + ni * 16 + l15] = bsq[ni];
    }
  }
  __syncthreads();                           // one draining barrier: loop done

  // ---- epilogue: scale by 1/max(||h_row||,eps) * 1/max(||w_col||,eps) ----
  // C/D layout: col = lane&15, row = quad*4 + reg
  const float wi0 = 1.0f / fmaxf(sqrtf(BssqL[col0]), 1e-12f);
  const float wi1 = 1.0f / fmaxf(sqrtf(BssqL[col0 + 16]), 1e-12f);

#pragma unroll
  for (int mi = 0; mi < 2; ++mi) {
#pragma unroll
    for (int r = 0; r < 4; ++r) {
      const int lr = wm * 32 + mi * 16 + quad * 4 + r;   // local row in tile
      const float hs = 1.0f / fmaxf(sqrtf(AssqL[lr]), 1e-12f);
      const int row = mt * 128 + lr;
      const size_t ob = ((size_t)row * Gn + g) * Kn + ntc * 64;
      out[ob + col0]      = acc[mi][0][r] * hs * wi0;
      out[ob + col0 + 16] = acc[mi][1][r] * hs * wi1;
    }
  }
}

extern "C" void kernel_launch(void* const* d_in, const int* in_sizes, int n_in,
                              void* d_out, int out_size, void* d_ws, size_t ws_size,
                              hipStream_t stream) {
  const float* h = (const float*)d_in[0];          // [B,G,D]
  const float* W = (const float*)d_in[1];          // [G,D,K]
  float* out = (float*)d_out;                      // [B,G,K]
  hipLaunchKernelGGL(groupfc_kernel, dim3(416), dim3(512), 0, stream, h, W, out);
}